// Round 8
// baseline (719.564 us; speedup 1.0000x reference)
//
#include <hip/hip_runtime.h>
#include <hip/hip_cooperative_groups.h>

namespace cg = cooperative_groups;

#define N 8192
#define L 13
#define SEGS 8
#define NSP (N / SEGS / 32)  // 32 MFMA-group iterations per filter wave
#define PARTROWS 416         // = N*L/256
#define FBLOCKS (128 * SEGS) // filter logical blocks
#define SMEMF (13 * 256 + 64)

typedef _Float16 f16x8 __attribute__((ext_vector_type(8)));
typedef _Float16 f16x2 __attribute__((ext_vector_type(2)));
typedef float f32x4 __attribute__((ext_vector_type(4)));
union F16x8U { f16x8 v; f16x2 h[4]; };

#define C1 (-0.72134752044448f)   // -0.5/ln2
#define C2 (1.44269504088896f)    // log2(e)
#define EBIAS 6.0f                // e' = exp2(C2*x - EBIAS); scale cancels in e'/D'

struct PP {
  const float *points, *logits, *Ws, *Wb, *Cm;
  float *cur, *crd, *snx, *snf, *ps, *pb, *S, *Bb, *M1, *M2, *part;
  unsigned short *a1pack, *qpack;
};

// ---------------- phase bodies (round-5 verified, blockIdx -> lb) ----------------

__device__ __forceinline__ void prep_body(int lb, int t, const PP& P, float* smem) {
  int p = lb * 256 + t;
  float c6[6];
#pragma unroll
  for (int d = 0; d < 6; ++d) { c6[d] = P.points[p * 6 + d]; P.crd[d * N + p] = c6[d]; }
  float sx = c6[0] * c6[0] + c6[1] * c6[1] + c6[2] * c6[2];
  float sf = c6[3] * c6[3] + c6[4] * c6[4] + c6[5] * c6[5];
  P.snx[p] = sx; P.snf[p] = sf;

  int spair = p >> 5, w = p & 31, rm = w & 15;
  int laneS = (w < 16 ? 0 : 32) + rm;
  int laneB = (w < 16 ? 16 : 48) + rm;
  f16x8 vs = { (_Float16)c6[0], (_Float16)c6[1], (_Float16)c6[2],
               (_Float16)sx, (_Float16)1.0f, (_Float16)0.0f, (_Float16)0.0f, (_Float16)0.0f };
  f16x8 vb = { (_Float16)c6[0], (_Float16)c6[1], (_Float16)c6[2],
               (_Float16)c6[3], (_Float16)c6[4], (_Float16)c6[5],
               (_Float16)(sx + sf), (_Float16)1.0f };
  ((f16x8*)P.a1pack)[(size_t)spair * 64 + laneS] = vs;
  ((f16x8*)P.a1pack)[(size_t)spair * 64 + laneB] = vb;

  int kc = p >> 5, kk = p & 31;
  int g = (kk < 16) ? (kk >> 2) : ((kk - 16) >> 2);
  int j2 = (kk < 16) ? (kk & 3) : (4 + (kk & 3));
  size_t qb = ((size_t)kc * 64 + g * 16) * 8 + j2;
  P.qpack[qb + 13 * 8] = 0x3C00;  // f16 1.0 (norm column)
  P.qpack[qb + 14 * 8] = 0;
  P.qpack[qb + 15 * 8] = 0;

  float (*buf)[256] = (float(*)[256])smem;
#pragma unroll
  for (int l = 0; l < L; ++l) {
    float e = __builtin_amdgcn_exp2f(P.logits[p * L + l] * C2 - EBIAS);
    _Float16 h = (_Float16)e;
    P.qpack[qb + (size_t)l * 8] = *(unsigned short*)&h;
    buf[l][t] = e;
  }
  __syncthreads();
  for (int s = 128; s >= 1; s >>= 1) {
    if (t < s) {
#pragma unroll
      for (int l = 0; l < L; ++l) buf[l][t] += buf[l][t + s];
    }
    __syncthreads();
  }
  if (t < L) P.part[lb * 16 + t] = buf[t][0];
  if (t < 192) P.part[(32 + lb * 12 + (t >> 4)) * 16 + (t & 15)] = 0.f;
}

__device__ __forceinline__ void mprep_body(int t, const PP& P) {
  if (t < L * L) {
    int r = t / L, c = t % L;
    float a = 0.f, b = 0.f;
    for (int j = 0; j < L; ++j) {
      a += P.Cm[r * L + j] * P.Ws[j * L + c];
      b += P.Cm[r * L + j] * P.Wb[j * L + c];
    }
    P.M1[t] = a; P.M2[t] = b;
  }
}

#define PK(dst, va, vb_) { auto _r = __builtin_amdgcn_cvt_pkrtz(va, vb_); dst = *(f16x2*)&_r; }
#define E(x) __builtin_amdgcn_exp2f(x)
#define MFMA16(a_, b_, c_) __builtin_amdgcn_mfma_f32_16x16x32_f16(a_, b_, c_, 0, 0, 0)

__device__ __forceinline__ void filter_body(int bx, int seg, int tid, const PP& P) {
  int lane = tid & 63, wave = tid >> 6;
  int g = lane >> 4, rm = lane & 15;
  int ptile = bx * 64 + wave * 16;
  int p = ptile + rm;

  float x0 = P.crd[p], x1 = P.crd[N + p], x2 = P.crd[2 * N + p];
  float f0 = P.crd[3 * N + p], f1 = P.crd[4 * N + p], f2 = P.crd[5 * N + p];
  float sx = P.snx[p], sf = P.snf[p];

  f16x8 spat = { (_Float16)(C2 * x0), (_Float16)(C2 * x1), (_Float16)(C2 * x2),
                 (_Float16)C1, (_Float16)(C1 * sx),
                 (_Float16)0.0f, (_Float16)0.0f, (_Float16)0.0f };
  f16x8 bil  = { (_Float16)(C2 * x0), (_Float16)(C2 * x1), (_Float16)(C2 * x2),
                 (_Float16)(C2 * f0), (_Float16)(C2 * f1), (_Float16)(C2 * f2),
                 (_Float16)C1, (_Float16)(C1 * (sx + sf)) };
  f16x8 z8 = {0, 0, 0, 0, 0, 0, 0, 0};
  f16x8 Bs0 = (g == 0) ? spat : z8;
  f16x8 Bb0 = (g == 1) ? bil : z8;
  f16x8 Bs1 = (g == 2) ? spat : z8;
  f16x8 Bb1 = (g == 3) ? bil : z8;

  f32x4 acc_s = {0.f, 0.f, 0.f, 0.f};
  f32x4 acc_b = {0.f, 0.f, 0.f, 0.f};
  const f32x4 zero = {0.f, 0.f, 0.f, 0.f};
  const f16x8* a1 = (const f16x8*)P.a1pack;
  const f16x8* qp = (const f16x8*)P.qpack;

  int sp0 = seg * NSP;
#pragma unroll 2
  for (int sp = sp0; sp < sp0 + NSP; ++sp) {
    f16x8 A  = a1[(size_t)sp * 64 + lane];
    f16x8 bq = qp[(size_t)sp * 64 + lane];
    f32x4 ax0 = MFMA16(A, Bs0, zero);
    f32x4 ab0 = MFMA16(A, Bb0, zero);
    f32x4 ax1 = MFMA16(A, Bs1, zero);
    f32x4 ab1 = MFMA16(A, Bb1, zero);
    F16x8U us, ub;
    PK(us.h[0], E(ax0[0]), E(ax0[1]));
    PK(us.h[1], E(ax0[2]), E(ax0[3]));
    PK(us.h[2], E(ax1[0]), E(ax1[1]));
    PK(us.h[3], E(ax1[2]), E(ax1[3]));
    PK(ub.h[0], E(ab0[0]), E(ab0[1]));
    PK(ub.h[1], E(ab0[2]), E(ab0[3]));
    PK(ub.h[2], E(ab1[0]), E(ab1[1]));
    PK(ub.h[3], E(ab1[2]), E(ab1[3]));
    acc_s = MFMA16(us.v, bq, acc_s);
    acc_b = MFMA16(ub.v, bq, acc_b);
  }

  int pout = ptile + g * 4;
  size_t base = ((size_t)seg * N + pout) * 16 + rm;
#pragma unroll
  for (int r = 0; r < 4; ++r) {
    P.ps[base + (size_t)r * 16] = acc_s[r];
    P.pb[base + (size_t)r * 16] = acc_b[r];
  }
}

__device__ __forceinline__ void reduce_body(int lb, int t, const PP& P, float* smem) {
  float (*buf)[256] = (float(*)[256])smem;
  float* nrm = smem + 13 * 256;
#pragma unroll
  for (int l = 0; l < L; ++l) {
    float v = P.part[t * 16 + l];
    if (t < PARTROWS - 256) v += P.part[(t + 256) * 16 + l];
    buf[l][t] = v;
  }
  __syncthreads();
  for (int s = 128; s >= 1; s >>= 1) {
    if (t < s) {
#pragma unroll
      for (int l = 0; l < L; ++l) buf[l][t] += buf[l][t + s];
    }
    __syncthreads();
  }

  int q = t & 3, src = (t >> 2) & 1, pi = t >> 3;
  int p = lb * 32 + pi;
  const float* basep = src ? P.pb : P.ps;
  f32x4 acc = {0.f, 0.f, 0.f, 0.f};
#pragma unroll
  for (int seg = 0; seg < SEGS; ++seg)
    acc += *(const f32x4*)(basep + ((size_t)seg * N + p) * 16 + q * 4);

  if (q == 3) nrm[pi * 2 + src] = acc[1];  // col 13 = norm
  __syncthreads();
  float inv_norm = 1.0f / nrm[pi * 2 + src];
  float* dst = src ? P.Bb : P.S;
#pragma unroll
  for (int e = 0; e < 4; ++e) {
    int col = q * 4 + e;
    if (col < L) {
      float invD = 1.0f / buf[col][0];
      dst[(size_t)p * L + col] = acc[e] * invD * inv_norm;
    }
  }
}

__device__ __forceinline__ void mix_body(int lb, int t, const PP& P, float* smem) {
  int i = lb * 256 + t;
  int c = i & (N - 1);
  int r = i >> 13;
  float v = 0.f;
#pragma unroll
  for (int j = 0; j < L; ++j) {
    v = fmaf(P.M1[r * L + j], P.S[(size_t)j * N + c], v);
    v = fmaf(P.M2[r * L + j], P.Bb[(size_t)j * N + c], v);
  }
  float o = v + P.logits[i];
  P.cur[i] = o;

  float e = __builtin_amdgcn_exp2f(o * C2 - EBIAS);
  unsigned int pr = (unsigned int)i / 13u;
  int l = i - pr * 13;
  int kc = pr >> 5, kk = pr & 31;
  int g = (kk < 16) ? (kk >> 2) : ((kk - 16) >> 2);
  int j2 = (kk < 16) ? (kk & 3) : (4 + (kk & 3));
  _Float16 h = (_Float16)e;
  P.qpack[((size_t)kc * 64 + g * 16 + l) * 8 + j2] = *(unsigned short*)&h;

  float* buf = smem;  // 260 floats
  if (t < 260) buf[t] = 0.f;
  __syncthreads();
  buf[l * 20 + t / 13u] = e;
  __syncthreads();
  if (t < L) {
    float s_ = 0.f;
#pragma unroll
    for (int k = 0; k < 20; ++k) s_ += buf[t * 20 + k];
    P.part[lb * 16 + t] = s_;
  }
}

// ---------------- cooperative mega-kernel ----------------

__global__ __launch_bounds__(256) void crf_coop(PP P) {
  __shared__ float smem[SMEMF];
  int t = threadIdx.x;
  cg::grid_group grid = cg::this_grid();

  for (int lb = blockIdx.x; lb < 33; lb += gridDim.x) {
    if (lb < 32) prep_body(lb, t, P, smem);
    else mprep_body(t, P);
  }
  grid.sync();

  for (int it = 0; it < 5; ++it) {
    for (int lb = blockIdx.x; lb < FBLOCKS; lb += gridDim.x)
      filter_body(lb & 127, lb >> 7, t, P);
    grid.sync();
    for (int lb = blockIdx.x; lb < 256; lb += gridDim.x)
      reduce_body(lb, t, P, smem);
    grid.sync();
    for (int lb = blockIdx.x; lb < PARTROWS; lb += gridDim.x)
      mix_body(lb, t, P, smem);
    if (it != 4) grid.sync();
  }
}

// ---------------- fallback classic kernels (same bodies) ----------------

__global__ __launch_bounds__(256) void prep_k(PP P) {
  __shared__ float smem[SMEMF];
  prep_body(blockIdx.x, threadIdx.x, P, smem);
}
__global__ void mprep_k(PP P) { mprep_body(threadIdx.x, P); }
__global__ __launch_bounds__(256) void filter_k(PP P) {
  filter_body(blockIdx.x, blockIdx.y, threadIdx.x, P);
}
__global__ __launch_bounds__(256) void reduce_k(PP P) {
  __shared__ float smem[SMEMF];
  reduce_body(blockIdx.x, threadIdx.x, P, smem);
}
__global__ __launch_bounds__(256) void mix_k(PP P) {
  __shared__ float smem[272];
  mix_body(blockIdx.x, threadIdx.x, P, smem);
}

extern "C" void kernel_launch(void* const* d_in, const int* in_sizes, int n_in,
                              void* d_out, int out_size, void* d_ws, size_t ws_size,
                              hipStream_t stream) {
  PP P;
  P.points = (const float*)d_in[0];
  P.logits = (const float*)d_in[1];
  P.Ws = (const float*)d_in[2];
  P.Wb = (const float*)d_in[3];
  P.Cm = (const float*)d_in[4];
  P.cur = (float*)d_out;

  float* w = (float*)d_ws;
  P.crd  = w;                        w += 6 * N;
  P.snx  = w;                        w += N;
  P.snf  = w;                        w += N;
  P.ps   = w;                        w += (size_t)SEGS * N * 16;
  P.pb   = w;                        w += (size_t)SEGS * N * 16;
  P.S    = w;                        w += (size_t)L * N + 64;
  P.Bb   = w;                        w += (size_t)L * N + 64;
  P.M1   = w;                        w += 256;
  P.M2   = w;                        w += 256;
  P.part = w;                        w += PARTROWS * 16;
  P.a1pack = (unsigned short*)w;                      // 256*64*8 u16 = 256 KB
  P.qpack  = P.a1pack + (size_t)256 * 64 * 8;         // 256 KB

  int nb = 0;
  (void)hipOccupancyMaxActiveBlocksPerMultiprocessor(&nb, crf_coop, 256, 0);
  int dev = 0;
  (void)hipGetDevice(&dev);
  hipDeviceProp_t prop{};
  (void)hipGetDeviceProperties(&prop, dev);
  long cap = (long)nb * (long)prop.multiProcessorCount;

  if (cap >= 128) {
    int G = cap < FBLOCKS ? (int)cap : FBLOCKS;
    void* args[] = { &P };
    (void)hipLaunchCooperativeKernel((void*)crf_coop, dim3(G), dim3(256), args, 0, stream);
  } else {
    prep_k<<<N / 256, 256, 0, stream>>>(P);
    mprep_k<<<1, 256, 0, stream>>>(P);
    for (int it = 0; it < 5; ++it) {
      filter_k<<<dim3(128, SEGS), 256, 0, stream>>>(P);
      reduce_k<<<256, 256, 0, stream>>>(P);
      mix_k<<<PARTROWS, 256, 0, stream>>>(P);
    }
  }
}

// Round 9
// 194.836 us; speedup vs baseline: 3.6932x; 3.6932x over previous
//
#include <hip/hip_runtime.h>

#define N 8192
#define L 13
#define SEGS 16
#define NSP (N / SEGS / 32)  // 16 MFMA-group iterations per filter wave
#define PARTROWS 416         // = N*L/256 (mix grid); prep fills rows 0..31, zeros rest

typedef _Float16 f16x8 __attribute__((ext_vector_type(8)));
typedef _Float16 f16x2 __attribute__((ext_vector_type(2)));
typedef float f32x4 __attribute__((ext_vector_type(4)));
union F16x8U { f16x8 v; f16x2 h[4]; };

#define C1 (-0.72134752044448f)   // -0.5/ln2
#define C2 (1.44269504088896f)    // log2(e)
#define EBIAS 6.0f                // e' = exp2(C2*x - EBIAS); scale cancels in e'/D'

// a1pack [spair(256)][lane(64)][j(8)] f16 — A-frags (k-side quintuple/octuple).
// qpack  [kc(256)][lane=g*16+col][j(8)] f16 = e'[kc*32+phys(g,j)][col]; col13=1.0, col14/15=0.
//   phys(g,j) = j<4 ? 4g+j : 16+4g+(j-4)

__global__ __launch_bounds__(256) void prep_kernel(const float* __restrict__ points,
                                                   const float* __restrict__ logits,
                                                   float* __restrict__ crd,
                                                   float* __restrict__ snx,
                                                   float* __restrict__ snf,
                                                   float* __restrict__ part,
                                                   unsigned short* __restrict__ a1pack,
                                                   unsigned short* __restrict__ qpack) {
  int t = threadIdx.x;
  int p = blockIdx.x * 256 + t;
  float c6[6];
#pragma unroll
  for (int d = 0; d < 6; ++d) { c6[d] = points[p * 6 + d]; crd[d * N + p] = c6[d]; }
  float sx = c6[0] * c6[0] + c6[1] * c6[1] + c6[2] * c6[2];
  float sf = c6[3] * c6[3] + c6[4] * c6[4] + c6[5] * c6[5];
  snx[p] = sx; snf[p] = sf;

  int spair = p >> 5, w = p & 31, rm = w & 15;
  int laneS = (w < 16 ? 0 : 32) + rm;
  int laneB = (w < 16 ? 16 : 48) + rm;
  f16x8 vs = { (_Float16)c6[0], (_Float16)c6[1], (_Float16)c6[2],
               (_Float16)sx, (_Float16)1.0f, (_Float16)0.0f, (_Float16)0.0f, (_Float16)0.0f };
  f16x8 vb = { (_Float16)c6[0], (_Float16)c6[1], (_Float16)c6[2],
               (_Float16)c6[3], (_Float16)c6[4], (_Float16)c6[5],
               (_Float16)(sx + sf), (_Float16)1.0f };
  ((f16x8*)a1pack)[(size_t)spair * 64 + laneS] = vs;
  ((f16x8*)a1pack)[(size_t)spair * 64 + laneB] = vb;

  int kc = p >> 5, kk = p & 31;
  int g = (kk < 16) ? (kk >> 2) : ((kk - 16) >> 2);
  int j2 = (kk < 16) ? (kk & 3) : (4 + (kk & 3));
  size_t qb = ((size_t)kc * 64 + g * 16) * 8 + j2;
  qpack[qb + 13 * 8] = 0x3C00;  // f16 1.0 (norm column)
  qpack[qb + 14 * 8] = 0;
  qpack[qb + 15 * 8] = 0;

  // initial unnormalized-softmax pack + per-block label sums
  __shared__ float buf[13][256];
#pragma unroll
  for (int l = 0; l < L; ++l) {
    float e = __builtin_amdgcn_exp2f(logits[p * L + l] * C2 - EBIAS);
    _Float16 h = (_Float16)e;
    qpack[qb + (size_t)l * 8] = *(unsigned short*)&h;
    buf[l][t] = e;
  }
  __syncthreads();
  for (int s = 128; s >= 1; s >>= 1) {
    if (t < s) {
#pragma unroll
      for (int l = 0; l < L; ++l) buf[l][t] += buf[l][t + s];
    }
    __syncthreads();
  }
  if (t < L) part[blockIdx.x * 16 + t] = buf[t][0];
  if (t < 192) part[(32 + blockIdx.x * 12 + (t >> 4)) * 16 + (t & 15)] = 0.f;
}

__global__ void mprep_kernel(const float* __restrict__ Ws, const float* __restrict__ Wb,
                             const float* __restrict__ C, float* __restrict__ M1,
                             float* __restrict__ M2) {
  int i = threadIdx.x;
  if (i < L * L) {
    int r = i / L, c = i % L;
    float a = 0.f, b = 0.f;
    for (int j = 0; j < L; ++j) {
      a += C[r * L + j] * Ws[j * L + c];
      b += C[r * L + j] * Wb[j * L + c];
    }
    M1[i] = a; M2[i] = b;
  }
}

// hot kernel: 4 independent waves/block, 16 p-rows each.
// Dot-MFMAs emit the complete exp2 arguments; VALU does only exp + pack.
__global__ __launch_bounds__(256) void filter_kernel(const float* __restrict__ crd,
                                                     const float* __restrict__ snx,
                                                     const float* __restrict__ snf,
                                                     const unsigned short* __restrict__ a1pack,
                                                     const unsigned short* __restrict__ qpack,
                                                     float* __restrict__ ps,
                                                     float* __restrict__ pb) {
  int tid = threadIdx.x;
  int lane = tid & 63, wave = tid >> 6;
  int g = lane >> 4, rm = lane & 15;
  int ptile = blockIdx.x * 64 + wave * 16;
  int p = ptile + rm;
  int seg = blockIdx.y;

  float x0 = crd[p], x1 = crd[N + p], x2 = crd[2 * N + p];
  float f0 = crd[3 * N + p], f1 = crd[4 * N + p], f2 = crd[5 * N + p];
  float sx = snx[p], sf = snf[p];

  f16x8 spat = { (_Float16)(C2 * x0), (_Float16)(C2 * x1), (_Float16)(C2 * x2),
                 (_Float16)C1, (_Float16)(C1 * sx),
                 (_Float16)0.0f, (_Float16)0.0f, (_Float16)0.0f };
  f16x8 bil  = { (_Float16)(C2 * x0), (_Float16)(C2 * x1), (_Float16)(C2 * x2),
                 (_Float16)(C2 * f0), (_Float16)(C2 * f1), (_Float16)(C2 * f2),
                 (_Float16)C1, (_Float16)(C1 * (sx + sf)) };
  f16x8 z8 = {0, 0, 0, 0, 0, 0, 0, 0};
  f16x8 Bs0 = (g == 0) ? spat : z8;
  f16x8 Bb0 = (g == 1) ? bil : z8;
  f16x8 Bs1 = (g == 2) ? spat : z8;
  f16x8 Bb1 = (g == 3) ? bil : z8;

  f32x4 acc_s = {0.f, 0.f, 0.f, 0.f};
  f32x4 acc_b = {0.f, 0.f, 0.f, 0.f};
  const f32x4 zero = {0.f, 0.f, 0.f, 0.f};
  const f16x8* a1 = (const f16x8*)a1pack;
  const f16x8* qp = (const f16x8*)qpack;

#define PK(dst, va, vb_) { auto _r = __builtin_amdgcn_cvt_pkrtz(va, vb_); dst = *(f16x2*)&_r; }
#define E(x) __builtin_amdgcn_exp2f(x)

  int sp0 = seg * NSP;
#pragma unroll 2
  for (int sp = sp0; sp < sp0 + NSP; ++sp) {
    f16x8 A  = a1[(size_t)sp * 64 + lane];
    f16x8 bq = qp[(size_t)sp * 64 + lane];
    f32x4 ax0 = __builtin_amdgcn_mfma_f32_16x16x32_f16(A, Bs0, zero, 0, 0, 0);
    f32x4 ab0 = __builtin_amdgcn_mfma_f32_16x16x32_f16(A, Bb0, zero, 0, 0, 0);
    f32x4 ax1 = __builtin_amdgcn_mfma_f32_16x16x32_f16(A, Bs1, zero, 0, 0, 0);
    f32x4 ab1 = __builtin_amdgcn_mfma_f32_16x16x32_f16(A, Bb1, zero, 0, 0, 0);
    F16x8U us, ub;
    PK(us.h[0], E(ax0[0]), E(ax0[1]));
    PK(us.h[1], E(ax0[2]), E(ax0[3]));
    PK(us.h[2], E(ax1[0]), E(ax1[1]));
    PK(us.h[3], E(ax1[2]), E(ax1[3]));
    PK(ub.h[0], E(ab0[0]), E(ab0[1]));
    PK(ub.h[1], E(ab0[2]), E(ab0[3]));
    PK(ub.h[2], E(ab1[0]), E(ab1[1]));
    PK(ub.h[3], E(ab1[2]), E(ab1[3]));
    acc_s = __builtin_amdgcn_mfma_f32_16x16x32_f16(us.v, bq, acc_s, 0, 0, 0);
    acc_b = __builtin_amdgcn_mfma_f32_16x16x32_f16(ub.v, bq, acc_b, 0, 0, 0);
  }

  // D layout: col(lane&15) = label slot, row = 4*(lane>>4)+r = p offset
  int pout = ptile + g * 4;
  size_t base = ((size_t)seg * N + pout) * 16 + rm;
#pragma unroll
  for (int r = 0; r < 4; ++r) {
    ps[base + (size_t)r * 16] = acc_s[r];
    pb[base + (size_t)r * 16] = acc_b[r];
  }
}

// 256 blocks; tasks = (point within 32) x (src: S/B) x (col-quad).
// Folds BOTH 1/norm (col 13) and 1/D_l (softmax denominator, from part) into S/Bb.
__global__ __launch_bounds__(256) void reduce_kernel(const float* __restrict__ ps,
                                                     const float* __restrict__ pb,
                                                     const float* __restrict__ part,
                                                     float* __restrict__ S,
                                                     float* __restrict__ Bb) {
  int t = threadIdx.x;
  __shared__ float buf[13][256];
#pragma unroll
  for (int l = 0; l < L; ++l) {
    float v = part[t * 16 + l];
    if (t < PARTROWS - 256) v += part[(t + 256) * 16 + l];
    buf[l][t] = v;
  }
  __syncthreads();
  for (int s = 128; s >= 1; s >>= 1) {
    if (t < s) {
#pragma unroll
      for (int l = 0; l < L; ++l) buf[l][t] += buf[l][t + s];
    }
    __syncthreads();
  }

  int q = t & 3, src = (t >> 2) & 1, pi = t >> 3;
  int p = blockIdx.x * 32 + pi;
  const float* basep = src ? pb : ps;
  f32x4 acc = {0.f, 0.f, 0.f, 0.f};
#pragma unroll
  for (int seg = 0; seg < SEGS; ++seg)
    acc += *(const f32x4*)(basep + ((size_t)seg * N + p) * 16 + q * 4);

  __shared__ float nrm[64];
  if (q == 3) nrm[pi * 2 + src] = acc[1];  // col 13 = norm
  __syncthreads();
  float inv_norm = 1.0f / nrm[pi * 2 + src];
  float* dst = src ? Bb : S;
#pragma unroll
  for (int e = 0; e < 4; ++e) {
    int col = q * 4 + e;
    if (col < L) {
      float invD = 1.0f / ((float*)buf)[col * 256];  // buf[col][0]
      dst[(size_t)p * L + col] = acc[e] * invD * inv_norm;
    }
  }
}

// faithful reshape-mixing + next iteration's unnormalized softmax pack + label partial sums
__global__ __launch_bounds__(256) void mix_kernel(const float* __restrict__ S,
                                                  const float* __restrict__ Bb,
                                                  const float* __restrict__ M1,
                                                  const float* __restrict__ M2,
                                                  const float* __restrict__ logits,
                                                  float* __restrict__ cur,
                                                  unsigned short* __restrict__ qpack,
                                                  float* __restrict__ part) {
  int t = threadIdx.x;
  int i = blockIdx.x * 256 + t;           // grid is exactly N*L/256 = 416
  int c = i & (N - 1);
  int r = i >> 13;
  float v = 0.f;
#pragma unroll
  for (int j = 0; j < L; ++j) {
    v = fmaf(M1[r * L + j], S[(size_t)j * N + c], v);
    v = fmaf(M2[r * L + j], Bb[(size_t)j * N + c], v);
  }
  float o = v + logits[i];
  cur[i] = o;

  float e = __builtin_amdgcn_exp2f(o * C2 - EBIAS);
  unsigned int pr = (unsigned int)i / 13u;
  int l = i - pr * 13;
  int kc = pr >> 5, kk = pr & 31;
  int g = (kk < 16) ? (kk >> 2) : ((kk - 16) >> 2);
  int j2 = (kk < 16) ? (kk & 3) : (4 + (kk & 3));
  _Float16 h = (_Float16)e;
  qpack[((size_t)kc * 64 + g * 16 + l) * 8 + j2] = *(unsigned short*)&h;

  // deterministic per-block label sums: slot (l, t/13) is bijective in t
  __shared__ float buf[260];
  if (t < 260) buf[t] = 0.f;
  __syncthreads();
  buf[l * 20 + t / 13u] = e;
  __syncthreads();
  if (t < L) {
    float s_ = 0.f;
#pragma unroll
    for (int k = 0; k < 20; ++k) s_ += buf[t * 20 + k];
    part[blockIdx.x * 16 + t] = s_;
  }
}

extern "C" void kernel_launch(void* const* d_in, const int* in_sizes, int n_in,
                              void* d_out, int out_size, void* d_ws, size_t ws_size,
                              hipStream_t stream) {
  const float* points = (const float*)d_in[0];
  const float* logits = (const float*)d_in[1];
  const float* Ws = (const float*)d_in[2];
  const float* Wb = (const float*)d_in[3];
  const float* C = (const float*)d_in[4];

  float* cur = (float*)d_out;

  float* w = (float*)d_ws;
  float* crd  = w;                        w += 6 * N;
  float* snx  = w;                        w += N;
  float* snf  = w;                        w += N;
  float* ps   = w;                        w += (size_t)SEGS * N * 16;
  float* pb   = w;                        w += (size_t)SEGS * N * 16;
  float* S    = w;                        w += (size_t)L * N + 64;
  float* Bb   = w;                        w += (size_t)L * N + 64;
  float* M1   = w;                        w += 256;
  float* M2   = w;                        w += 256;
  float* part = w;                        w += PARTROWS * 16;
  unsigned short* a1pack = (unsigned short*)w;              // 256*64*8 u16 = 256 KB
  unsigned short* qpack  = a1pack + (size_t)256 * 64 * 8;   // 256 KB

  prep_kernel<<<N / 256, 256, 0, stream>>>(points, logits, crd, snx, snf, part, a1pack, qpack);
  mprep_kernel<<<1, 256, 0, stream>>>(Ws, Wb, C, M1, M2);

  for (int it = 0; it < 5; ++it) {
    filter_kernel<<<dim3(N / 64, SEGS), 256, 0, stream>>>(crd, snx, snf, a1pack, qpack, ps, pb);
    reduce_kernel<<<N / 32, 256, 0, stream>>>(ps, pb, part, S, Bb);
    mix_kernel<<<(N * L) / 256, 256, 0, stream>>>(S, Bb, M1, M2, logits, cur, qpack, part);
  }
}

// Round 10
// 161.510 us; speedup vs baseline: 4.4552x; 1.2063x over previous
//
#include <hip/hip_runtime.h>

#define N 8192
#define L 13
#define SEGS 8
#define NSP (N / SEGS / 32)  // 32 MFMA-group iterations per filter wave

typedef _Float16 f16x8 __attribute__((ext_vector_type(8)));
typedef _Float16 f16x2 __attribute__((ext_vector_type(2)));
typedef float f32x4 __attribute__((ext_vector_type(4)));
union F16x8U { f16x8 v; f16x2 h[4]; };

#define C1 (-0.72134752044448f)   // -0.5/ln2
#define C2 (1.44269504088896f)    // log2(e)
#define EBIAS 6.0f                // e' = exp2(C2*x - EBIAS); scale cancels in e'/D'

// a1pack [spair(256)][lane(64)][j(8)] f16 — A-frags (k-side quintuple/octuple).
// qpack  [kc(256)][lane=g*16+col][j(8)] f16 = e'[kc*32+phys(g,j)][col]; col13=1.0, col14/15=0.
//   phys(g,j) = j<4 ? 4g+j : 16+4g+(j-4)
// part   [row][16]: per-writer-block unnormalized softmax label sums (rows 0..31 from prep,
//        rows 0..255 from redmix); reader sums first R rows.

__global__ __launch_bounds__(256) void prep_kernel(const float* __restrict__ points,
                                                   const float* __restrict__ logits,
                                                   const float* __restrict__ Ws,
                                                   const float* __restrict__ Wb,
                                                   const float* __restrict__ Cm,
                                                   float* __restrict__ crd,
                                                   float* __restrict__ snx,
                                                   float* __restrict__ snf,
                                                   float* __restrict__ part,
                                                   float* __restrict__ M1,
                                                   float* __restrict__ M2,
                                                   unsigned short* __restrict__ a1pack,
                                                   unsigned short* __restrict__ qpack) {
  int t = threadIdx.x;
  if (blockIdx.x == 32) {  // fused mprep
    if (t < L * L) {
      int r = t / L, c = t % L;
      float a = 0.f, b = 0.f;
      for (int j = 0; j < L; ++j) {
        a += Cm[r * L + j] * Ws[j * L + c];
        b += Cm[r * L + j] * Wb[j * L + c];
      }
      M1[t] = a; M2[t] = b;
    }
    return;
  }
  int p = blockIdx.x * 256 + t;
  float c6[6];
#pragma unroll
  for (int d = 0; d < 6; ++d) { c6[d] = points[p * 6 + d]; crd[d * N + p] = c6[d]; }
  float sx = c6[0] * c6[0] + c6[1] * c6[1] + c6[2] * c6[2];
  float sf = c6[3] * c6[3] + c6[4] * c6[4] + c6[5] * c6[5];
  snx[p] = sx; snf[p] = sf;

  int spair = p >> 5, w = p & 31, rm = w & 15;
  int laneS = (w < 16 ? 0 : 32) + rm;
  int laneB = (w < 16 ? 16 : 48) + rm;
  f16x8 vs = { (_Float16)c6[0], (_Float16)c6[1], (_Float16)c6[2],
               (_Float16)sx, (_Float16)1.0f, (_Float16)0.0f, (_Float16)0.0f, (_Float16)0.0f };
  f16x8 vb = { (_Float16)c6[0], (_Float16)c6[1], (_Float16)c6[2],
               (_Float16)c6[3], (_Float16)c6[4], (_Float16)c6[5],
               (_Float16)(sx + sf), (_Float16)1.0f };
  ((f16x8*)a1pack)[(size_t)spair * 64 + laneS] = vs;
  ((f16x8*)a1pack)[(size_t)spair * 64 + laneB] = vb;

  int kc = p >> 5, kk = p & 31;
  int g = (kk < 16) ? (kk >> 2) : ((kk - 16) >> 2);
  int j2 = (kk < 16) ? (kk & 3) : (4 + (kk & 3));
  size_t qb = ((size_t)kc * 64 + g * 16) * 8 + j2;
  qpack[qb + 13 * 8] = 0x3C00;  // f16 1.0 (norm column)
  qpack[qb + 14 * 8] = 0;
  qpack[qb + 15 * 8] = 0;

  // initial unnormalized-softmax pack + per-block label sums
  __shared__ float buf[13][256];
#pragma unroll
  for (int l = 0; l < L; ++l) {
    float e = __builtin_amdgcn_exp2f(logits[p * L + l] * C2 - EBIAS);
    _Float16 h = (_Float16)e;
    qpack[qb + (size_t)l * 8] = *(unsigned short*)&h;
    buf[l][t] = e;
  }
  __syncthreads();
  for (int s = 128; s >= 1; s >>= 1) {
    if (t < s) {
#pragma unroll
      for (int l = 0; l < L; ++l) buf[l][t] += buf[l][t + s];
    }
    __syncthreads();
  }
  if (t < L) part[blockIdx.x * 16 + t] = buf[t][0];
}

// hot kernel: 4 independent waves/block, 16 p-rows each (round-5 verified optimum).
__global__ __launch_bounds__(256) void filter_kernel(const float* __restrict__ crd,
                                                     const float* __restrict__ snx,
                                                     const float* __restrict__ snf,
                                                     const unsigned short* __restrict__ a1pack,
                                                     const unsigned short* __restrict__ qpack,
                                                     float* __restrict__ ps,
                                                     float* __restrict__ pb) {
  int tid = threadIdx.x;
  int lane = tid & 63, wave = tid >> 6;
  int g = lane >> 4, rm = lane & 15;
  int ptile = blockIdx.x * 64 + wave * 16;
  int p = ptile + rm;
  int seg = blockIdx.y;

  float x0 = crd[p], x1 = crd[N + p], x2 = crd[2 * N + p];
  float f0 = crd[3 * N + p], f1 = crd[4 * N + p], f2 = crd[5 * N + p];
  float sx = snx[p], sf = snf[p];

  f16x8 spat = { (_Float16)(C2 * x0), (_Float16)(C2 * x1), (_Float16)(C2 * x2),
                 (_Float16)C1, (_Float16)(C1 * sx),
                 (_Float16)0.0f, (_Float16)0.0f, (_Float16)0.0f };
  f16x8 bil  = { (_Float16)(C2 * x0), (_Float16)(C2 * x1), (_Float16)(C2 * x2),
                 (_Float16)(C2 * f0), (_Float16)(C2 * f1), (_Float16)(C2 * f2),
                 (_Float16)C1, (_Float16)(C1 * (sx + sf)) };
  f16x8 z8 = {0, 0, 0, 0, 0, 0, 0, 0};
  f16x8 Bs0 = (g == 0) ? spat : z8;
  f16x8 Bb0 = (g == 1) ? bil : z8;
  f16x8 Bs1 = (g == 2) ? spat : z8;
  f16x8 Bb1 = (g == 3) ? bil : z8;

  f32x4 acc_s = {0.f, 0.f, 0.f, 0.f};
  f32x4 acc_b = {0.f, 0.f, 0.f, 0.f};
  const f32x4 zero = {0.f, 0.f, 0.f, 0.f};
  const f16x8* a1 = (const f16x8*)a1pack;
  const f16x8* qp = (const f16x8*)qpack;

#define PK(dst, va, vb_) { auto _r = __builtin_amdgcn_cvt_pkrtz(va, vb_); dst = *(f16x2*)&_r; }
#define E(x) __builtin_amdgcn_exp2f(x)

  int sp0 = seg * NSP;
#pragma unroll 2
  for (int sp = sp0; sp < sp0 + NSP; ++sp) {
    f16x8 A  = a1[(size_t)sp * 64 + lane];
    f16x8 bq = qp[(size_t)sp * 64 + lane];
    f32x4 ax0 = __builtin_amdgcn_mfma_f32_16x16x32_f16(A, Bs0, zero, 0, 0, 0);
    f32x4 ab0 = __builtin_amdgcn_mfma_f32_16x16x32_f16(A, Bb0, zero, 0, 0, 0);
    f32x4 ax1 = __builtin_amdgcn_mfma_f32_16x16x32_f16(A, Bs1, zero, 0, 0, 0);
    f32x4 ab1 = __builtin_amdgcn_mfma_f32_16x16x32_f16(A, Bb1, zero, 0, 0, 0);
    F16x8U us, ub;
    PK(us.h[0], E(ax0[0]), E(ax0[1]));
    PK(us.h[1], E(ax0[2]), E(ax0[3]));
    PK(us.h[2], E(ax1[0]), E(ax1[1]));
    PK(us.h[3], E(ax1[2]), E(ax1[3]));
    PK(ub.h[0], E(ab0[0]), E(ab0[1]));
    PK(ub.h[1], E(ab0[2]), E(ab0[3]));
    PK(ub.h[2], E(ab1[0]), E(ab1[1]));
    PK(ub.h[3], E(ab1[2]), E(ab1[3]));
    acc_s = __builtin_amdgcn_mfma_f32_16x16x32_f16(us.v, bq, acc_s, 0, 0, 0);
    acc_b = __builtin_amdgcn_mfma_f32_16x16x32_f16(ub.v, bq, acc_b, 0, 0, 0);
  }

  // D layout: col(lane&15) = label slot, row = 4*(lane>>4)+r = p offset
  int pout = ptile + g * 4;
  size_t base = ((size_t)seg * N + pout) * 16 + rm;
#pragma unroll
  for (int r = 0; r < 4; ++r) {
    ps[base + (size_t)r * 16] = acc_s[r];
    pb[base + (size_t)r * 16] = acc_b[r];
  }
}

// fused reduce+mix: 256 blocks, each owns 32 points (all labels).
// Phase A: seg-sum partials, fold 1/norm and 1/D_l, keep S/Bb in LDS.
// Phase B: reshape-mix 13x32 outputs, write cur, pack next softmax, emit label sums.
__global__ __launch_bounds__(256) void redmix_kernel(const float* __restrict__ ps,
                                                     const float* __restrict__ pb,
                                                     float* __restrict__ part,
                                                     const float* __restrict__ M1,
                                                     const float* __restrict__ M2,
                                                     const float* __restrict__ logits,
                                                     float* __restrict__ cur,
                                                     unsigned short* __restrict__ qpack,
                                                     int R) {
  int t = threadIdx.x;
  __shared__ float buf[13][256];
  __shared__ float nrm[64];
  __shared__ float sAB[2][32][13];
  __shared__ float m1s[169], m2s[169];
  __shared__ float ebuf[416];

  // softmax denominators: tree over R part rows (all blocks replicate; cheap)
#pragma unroll
  for (int l = 0; l < L; ++l) buf[l][t] = (t < R) ? part[t * 16 + l] : 0.f;
  if (t < 169) { m1s[t] = M1[t]; m2s[t] = M2[t]; }
  __syncthreads();
  for (int s = 128; s >= 1; s >>= 1) {
    if (t < s) {
#pragma unroll
      for (int l = 0; l < L; ++l) buf[l][t] += buf[l][t + s];
    }
    __syncthreads();
  }

  // phase A: per-point seg reduction; tasks = (pi, src, quad)
  int q = t & 3, src = (t >> 2) & 1, pi = t >> 3;
  int p = blockIdx.x * 32 + pi;
  const float* basep = src ? pb : ps;
  f32x4 acc = {0.f, 0.f, 0.f, 0.f};
#pragma unroll
  for (int seg = 0; seg < SEGS; ++seg)
    acc += *(const f32x4*)(basep + ((size_t)seg * N + p) * 16 + q * 4);

  if (q == 3) nrm[pi * 2 + src] = acc[1];  // col 13 = norm
  __syncthreads();
  float inv_norm = 1.0f / nrm[pi * 2 + src];
#pragma unroll
  for (int e = 0; e < 4; ++e) {
    int col = q * 4 + e;
    if (col < L) sAB[src][pi][col] = acc[e] * (1.0f / buf[col][0]) * inv_norm;
  }
  __syncthreads();

  // phase B: mix outputs for c in [p0, p0+32), r in [0,13)
  int p0 = blockIdx.x * 32;
#pragma unroll 2
  for (int oi = t; oi < 416; oi += 256) {
    int r = oi >> 5, ci = oi & 31;
    float v = 0.f;
#pragma unroll
    for (int j = 0; j < L; ++j) {
      v = fmaf(m1s[r * L + j], sAB[0][ci][j], v);
      v = fmaf(m2s[r * L + j], sAB[1][ci][j], v);
    }
    int i = (r << 13) + p0 + ci;
    float o = v + logits[i];
    cur[i] = o;
    float e = __builtin_amdgcn_exp2f(o * C2 - EBIAS);
    ebuf[oi] = e;
    unsigned int pr = (unsigned int)i / 13u;
    int l = i - pr * 13;
    int kc = pr >> 5, kk = pr & 31;
    int g = (kk < 16) ? (kk >> 2) : ((kk - 16) >> 2);
    int j2 = (kk < 16) ? (kk & 3) : (4 + (kk & 3));
    _Float16 h = (_Float16)e;
    qpack[((size_t)kc * 64 + g * 16 + l) * 8 + j2] = *(unsigned short*)&h;
  }
  __syncthreads();

  // label sums of ebuf: flat%13 = (2r + p0 + ci) % 13  (8192 mod 13 == 2)
  if (t < L) {
    float s_ = 0.f;
#pragma unroll
    for (int r = 0; r < L; ++r) {
      int base = (t - p0 - 2 * r) % 13;
      base = (base + 13) % 13;
      float a0 = ebuf[r * 32 + base];
      float a1_ = (base + 13 < 32) ? ebuf[r * 32 + base + 13] : 0.f;
      float a2 = (base + 26 < 32) ? ebuf[r * 32 + base + 26] : 0.f;
      s_ += a0 + a1_ + a2;
    }
    part[blockIdx.x * 16 + t] = s_;
  }
}

extern "C" void kernel_launch(void* const* d_in, const int* in_sizes, int n_in,
                              void* d_out, int out_size, void* d_ws, size_t ws_size,
                              hipStream_t stream) {
  const float* points = (const float*)d_in[0];
  const float* logits = (const float*)d_in[1];
  const float* Ws = (const float*)d_in[2];
  const float* Wb = (const float*)d_in[3];
  const float* Cm = (const float*)d_in[4];

  float* cur = (float*)d_out;

  float* w = (float*)d_ws;
  float* crd  = w;                        w += 6 * N;
  float* snx  = w;                        w += N;
  float* snf  = w;                        w += N;
  float* ps   = w;                        w += (size_t)SEGS * N * 16;
  float* pb   = w;                        w += (size_t)SEGS * N * 16;
  float* M1   = w;                        w += 256;
  float* M2   = w;                        w += 256;
  float* part = w;                        w += 256 * 16;
  unsigned short* a1pack = (unsigned short*)w;              // 256*64*8 u16 = 256 KB
  unsigned short* qpack  = a1pack + (size_t)256 * 64 * 8;   // 256 KB

  prep_kernel<<<33, 256, 0, stream>>>(points, logits, Ws, Wb, Cm, crd, snx, snf,
                                      part, M1, M2, a1pack, qpack);

  for (int it = 0; it < 5; ++it) {
    filter_kernel<<<dim3(N / 64, SEGS), 256, 0, stream>>>(crd, snx, snf, a1pack, qpack, ps, pb);
    redmix_kernel<<<256, 256, 0, stream>>>(ps, pb, part, M1, M2, logits, cur, qpack,
                                           it == 0 ? 32 : 256);
  }
}

// Round 11
// 150.507 us; speedup vs baseline: 4.7809x; 1.0731x over previous
//
#include <hip/hip_runtime.h>

#define N 8192
#define L 13
#define SEGS 8
#define NSP (N / SEGS / 32)  // 32 MFMA-group iterations per filter wave

typedef _Float16 f16x8 __attribute__((ext_vector_type(8)));
typedef _Float16 f16x2 __attribute__((ext_vector_type(2)));
typedef float f32x4 __attribute__((ext_vector_type(4)));
union F16x8U { f16x8 v; f16x2 h[4]; };

#define C1 (-0.72134752044448f)   // -0.5/ln2
#define C2 (1.44269504088896f)    // log2(e)
#define EBIAS 6.0f                // e' = exp2(C2*x - EBIAS); scale cancels in e'/D'

// a1pack [spair(256)][lane(64)][j(8)] f16 — A-frags (k-side quintuple/octuple).
// qpack  [kc(256)][lane=g*16+col][j(8)] f16 = e'[kc*32+phys(g,j)][col]; col13=1.0, col14/15=0.
// psh/pbh: f16 partials [seg][point][16] (13 labels + norm@13 + pad).
// part   [row][16] f32: per-block unnormalized softmax label sums.

__global__ __launch_bounds__(256) void prep_kernel(const float* __restrict__ points,
                                                   const float* __restrict__ logits,
                                                   const float* __restrict__ Ws,
                                                   const float* __restrict__ Wb,
                                                   const float* __restrict__ Cm,
                                                   float* __restrict__ crd,
                                                   float* __restrict__ snx,
                                                   float* __restrict__ snf,
                                                   float* __restrict__ part,
                                                   float* __restrict__ M1,
                                                   float* __restrict__ M2,
                                                   unsigned short* __restrict__ a1pack,
                                                   unsigned short* __restrict__ qpack) {
  int t = threadIdx.x;
  if (blockIdx.x == 32) {  // fused mprep
    if (t < L * L) {
      int r = t / L, c = t % L;
      float a = 0.f, b = 0.f;
      for (int j = 0; j < L; ++j) {
        a += Cm[r * L + j] * Ws[j * L + c];
        b += Cm[r * L + j] * Wb[j * L + c];
      }
      M1[t] = a; M2[t] = b;
    }
    return;
  }
  int p = blockIdx.x * 256 + t;
  float c6[6];
#pragma unroll
  for (int d = 0; d < 6; ++d) { c6[d] = points[p * 6 + d]; crd[d * N + p] = c6[d]; }
  float sx = c6[0] * c6[0] + c6[1] * c6[1] + c6[2] * c6[2];
  float sf = c6[3] * c6[3] + c6[4] * c6[4] + c6[5] * c6[5];
  snx[p] = sx; snf[p] = sf;

  int spair = p >> 5, w = p & 31, rm = w & 15;
  int laneS = (w < 16 ? 0 : 32) + rm;
  int laneB = (w < 16 ? 16 : 48) + rm;
  f16x8 vs = { (_Float16)c6[0], (_Float16)c6[1], (_Float16)c6[2],
               (_Float16)sx, (_Float16)1.0f, (_Float16)0.0f, (_Float16)0.0f, (_Float16)0.0f };
  f16x8 vb = { (_Float16)c6[0], (_Float16)c6[1], (_Float16)c6[2],
               (_Float16)c6[3], (_Float16)c6[4], (_Float16)c6[5],
               (_Float16)(sx + sf), (_Float16)1.0f };
  ((f16x8*)a1pack)[(size_t)spair * 64 + laneS] = vs;
  ((f16x8*)a1pack)[(size_t)spair * 64 + laneB] = vb;

  int kc = p >> 5, kk = p & 31;
  int g = (kk < 16) ? (kk >> 2) : ((kk - 16) >> 2);
  int j2 = (kk < 16) ? (kk & 3) : (4 + (kk & 3));
  size_t qb = ((size_t)kc * 64 + g * 16) * 8 + j2;
  qpack[qb + 13 * 8] = 0x3C00;  // f16 1.0 (norm column)
  qpack[qb + 14 * 8] = 0;
  qpack[qb + 15 * 8] = 0;

  // initial unnormalized-softmax pack + per-block label sums
  __shared__ float buf[13][256];
#pragma unroll
  for (int l = 0; l < L; ++l) {
    float e = __builtin_amdgcn_exp2f(logits[p * L + l] * C2 - EBIAS);
    _Float16 h = (_Float16)e;
    qpack[qb + (size_t)l * 8] = *(unsigned short*)&h;
    buf[l][t] = e;
  }
  __syncthreads();
  for (int s = 128; s >= 1; s >>= 1) {
    if (t < s) {
#pragma unroll
      for (int l = 0; l < L; ++l) buf[l][t] += buf[l][t + s];
    }
    __syncthreads();
  }
  if (t < L) part[blockIdx.x * 16 + t] = buf[t][0];
}

// hot kernel: 4 independent waves/block, 16 p-rows each (round-5 verified optimum).
// Epilogue stores f16 partials (halved write traffic).
__global__ __launch_bounds__(256) void filter_kernel(const float* __restrict__ crd,
                                                     const float* __restrict__ snx,
                                                     const float* __restrict__ snf,
                                                     const unsigned short* __restrict__ a1pack,
                                                     const unsigned short* __restrict__ qpack,
                                                     unsigned short* __restrict__ psh,
                                                     unsigned short* __restrict__ pbh) {
  int tid = threadIdx.x;
  int lane = tid & 63, wave = tid >> 6;
  int g = lane >> 4, rm = lane & 15;
  int ptile = blockIdx.x * 64 + wave * 16;
  int p = ptile + rm;
  int seg = blockIdx.y;

  float x0 = crd[p], x1 = crd[N + p], x2 = crd[2 * N + p];
  float f0 = crd[3 * N + p], f1 = crd[4 * N + p], f2 = crd[5 * N + p];
  float sx = snx[p], sf = snf[p];

  f16x8 spat = { (_Float16)(C2 * x0), (_Float16)(C2 * x1), (_Float16)(C2 * x2),
                 (_Float16)C1, (_Float16)(C1 * sx),
                 (_Float16)0.0f, (_Float16)0.0f, (_Float16)0.0f };
  f16x8 bil  = { (_Float16)(C2 * x0), (_Float16)(C2 * x1), (_Float16)(C2 * x2),
                 (_Float16)(C2 * f0), (_Float16)(C2 * f1), (_Float16)(C2 * f2),
                 (_Float16)C1, (_Float16)(C1 * (sx + sf)) };
  f16x8 z8 = {0, 0, 0, 0, 0, 0, 0, 0};
  f16x8 Bs0 = (g == 0) ? spat : z8;
  f16x8 Bb0 = (g == 1) ? bil : z8;
  f16x8 Bs1 = (g == 2) ? spat : z8;
  f16x8 Bb1 = (g == 3) ? bil : z8;

  f32x4 acc_s = {0.f, 0.f, 0.f, 0.f};
  f32x4 acc_b = {0.f, 0.f, 0.f, 0.f};
  const f32x4 zero = {0.f, 0.f, 0.f, 0.f};
  const f16x8* a1 = (const f16x8*)a1pack;
  const f16x8* qp = (const f16x8*)qpack;

#define PK(dst, va, vb_) { auto _r = __builtin_amdgcn_cvt_pkrtz(va, vb_); dst = *(f16x2*)&_r; }
#define E(x) __builtin_amdgcn_exp2f(x)

  int sp0 = seg * NSP;
#pragma unroll 2
  for (int sp = sp0; sp < sp0 + NSP; ++sp) {
    f16x8 A  = a1[(size_t)sp * 64 + lane];
    f16x8 bq = qp[(size_t)sp * 64 + lane];
    f32x4 ax0 = __builtin_amdgcn_mfma_f32_16x16x32_f16(A, Bs0, zero, 0, 0, 0);
    f32x4 ab0 = __builtin_amdgcn_mfma_f32_16x16x32_f16(A, Bb0, zero, 0, 0, 0);
    f32x4 ax1 = __builtin_amdgcn_mfma_f32_16x16x32_f16(A, Bs1, zero, 0, 0, 0);
    f32x4 ab1 = __builtin_amdgcn_mfma_f32_16x16x32_f16(A, Bb1, zero, 0, 0, 0);
    F16x8U us, ub;
    PK(us.h[0], E(ax0[0]), E(ax0[1]));
    PK(us.h[1], E(ax0[2]), E(ax0[3]));
    PK(us.h[2], E(ax1[0]), E(ax1[1]));
    PK(us.h[3], E(ax1[2]), E(ax1[3]));
    PK(ub.h[0], E(ab0[0]), E(ab0[1]));
    PK(ub.h[1], E(ab0[2]), E(ab0[3]));
    PK(ub.h[2], E(ab1[0]), E(ab1[1]));
    PK(ub.h[3], E(ab1[2]), E(ab1[3]));
    acc_s = __builtin_amdgcn_mfma_f32_16x16x32_f16(us.v, bq, acc_s, 0, 0, 0);
    acc_b = __builtin_amdgcn_mfma_f32_16x16x32_f16(ub.v, bq, acc_b, 0, 0, 0);
  }

  // D layout: col(lane&15) = label slot, row = 4*(lane>>4)+r = p offset
  int pout = ptile + g * 4;
  size_t base = ((size_t)seg * N + pout) * 16 + rm;
#pragma unroll
  for (int r = 0; r < 4; ++r) {
    _Float16 hs = (_Float16)acc_s[r];
    _Float16 hb = (_Float16)acc_b[r];
    psh[base + (size_t)r * 16] = *(unsigned short*)&hs;
    pbh[base + (size_t)r * 16] = *(unsigned short*)&hb;
  }
}

// fused reduce+mix: 256 blocks, each owns 32 points (all labels).
// Phase A (t<128): f16x8 seg-sums; fold 1/norm and 1/D_l; S/Bb stay in LDS.
// Phase B: reshape-mix 13x32 outputs, write cur; if !last, pack next softmax + label sums.
__global__ __launch_bounds__(256) void redmix_kernel(const unsigned short* __restrict__ psh,
                                                     const unsigned short* __restrict__ pbh,
                                                     float* __restrict__ part,
                                                     const float* __restrict__ M1,
                                                     const float* __restrict__ M2,
                                                     const float* __restrict__ logits,
                                                     float* __restrict__ cur,
                                                     unsigned short* __restrict__ qpack,
                                                     int R, int last) {
  int t = threadIdx.x;
  __shared__ float buf[13][256];
  __shared__ float nrm[64];
  __shared__ float sAB[2][32][13];
  __shared__ float m1s[169], m2s[169];
  __shared__ float ebuf[416];

  // softmax denominators: tree over R part rows
#pragma unroll
  for (int l = 0; l < L; ++l) buf[l][t] = (t < R) ? part[t * 16 + l] : 0.f;
  if (t < 169) { m1s[t] = M1[t]; m2s[t] = M2[t]; }
  __syncthreads();
  for (int s = 128; s >= 1; s >>= 1) {
    if (t < s) {
#pragma unroll
      for (int l = 0; l < L; ++l) buf[l][t] += buf[l][t + s];
    }
    __syncthreads();
  }

  // phase A: tasks (t<128) = (pi, src, half-of-cols); f16x8 loads over 8 segs
  int pi = t >> 2, src = (t >> 1) & 1, half = t & 1;
  float a8[8] = {0.f, 0.f, 0.f, 0.f, 0.f, 0.f, 0.f, 0.f};
  if (t < 128) {
    int p = blockIdx.x * 32 + pi;
    const unsigned short* basep = src ? pbh : psh;
#pragma unroll
    for (int seg = 0; seg < SEGS; ++seg) {
      f16x8 v = *(const f16x8*)(basep + ((size_t)seg * N + p) * 16 + half * 8);
#pragma unroll
      for (int j = 0; j < 8; ++j) a8[j] += (float)v[j];
    }
    if (half == 1) nrm[pi * 2 + src] = a8[5];  // col 13 = norm
  }
  __syncthreads();
  if (t < 128) {
    float inv_norm = 1.0f / nrm[pi * 2 + src];
#pragma unroll
    for (int j = 0; j < 8; ++j) {
      int col = half * 8 + j;
      if (col < L) sAB[src][pi][col] = a8[j] * (1.0f / buf[col][0]) * inv_norm;
    }
  }
  __syncthreads();

  // phase B: mix outputs for c in [p0, p0+32), r in [0,13)
  int p0 = blockIdx.x * 32;
#pragma unroll 2
  for (int oi = t; oi < 416; oi += 256) {
    int r = oi >> 5, ci = oi & 31;
    float v = 0.f;
#pragma unroll
    for (int j = 0; j < L; ++j) {
      v = fmaf(m1s[r * L + j], sAB[0][ci][j], v);
      v = fmaf(m2s[r * L + j], sAB[1][ci][j], v);
    }
    int i = (r << 13) + p0 + ci;
    float o = v + logits[i];
    cur[i] = o;
    if (!last) {
      float e = __builtin_amdgcn_exp2f(o * C2 - EBIAS);
      ebuf[oi] = e;
      unsigned int pr = (unsigned int)i / 13u;
      int l = i - pr * 13;
      int kc = pr >> 5, kk = pr & 31;
      int g = (kk < 16) ? (kk >> 2) : ((kk - 16) >> 2);
      int j2 = (kk < 16) ? (kk & 3) : (4 + (kk & 3));
      _Float16 h = (_Float16)e;
      qpack[((size_t)kc * 64 + g * 16 + l) * 8 + j2] = *(unsigned short*)&h;
    }
  }
  if (last) return;
  __syncthreads();

  // label sums of ebuf: flat%13 = (2r + p0 + ci) % 13  (8192 mod 13 == 2)
  if (t < L) {
    float s_ = 0.f;
#pragma unroll
    for (int r = 0; r < L; ++r) {
      int base = (t - p0 - 2 * r) % 13;
      base = (base + 13) % 13;
      float a0 = ebuf[r * 32 + base];
      float a1_ = (base + 13 < 32) ? ebuf[r * 32 + base + 13] : 0.f;
      float a2 = (base + 26 < 32) ? ebuf[r * 32 + base + 26] : 0.f;
      s_ += a0 + a1_ + a2;
    }
    part[blockIdx.x * 16 + t] = s_;
  }
}

extern "C" void kernel_launch(void* const* d_in, const int* in_sizes, int n_in,
                              void* d_out, int out_size, void* d_ws, size_t ws_size,
                              hipStream_t stream) {
  const float* points = (const float*)d_in[0];
  const float* logits = (const float*)d_in[1];
  const float* Ws = (const float*)d_in[2];
  const float* Wb = (const float*)d_in[3];
  const float* Cm = (const float*)d_in[4];

  float* cur = (float*)d_out;

  float* w = (float*)d_ws;
  float* crd  = w;                        w += 6 * N;
  float* snx  = w;                        w += N;
  float* snf  = w;                        w += N;
  float* M1   = w;                        w += 256;
  float* M2   = w;                        w += 256;
  float* part = w;                        w += 256 * 16;
  unsigned short* psh = (unsigned short*)w;                 // SEGS*N*16 u16 = 4.2 MB
  unsigned short* pbh = psh + (size_t)SEGS * N * 16;        // 4.2 MB
  unsigned short* a1pack = pbh + (size_t)SEGS * N * 16;     // 256 KB
  unsigned short* qpack  = a1pack + (size_t)256 * 64 * 8;   // 256 KB

  prep_kernel<<<33, 256, 0, stream>>>(points, logits, Ws, Wb, Cm, crd, snx, snf,
                                      part, M1, M2, a1pack, qpack);

  for (int it = 0; it < 5; ++it) {
    filter_kernel<<<dim3(N / 64, SEGS), 256, 0, stream>>>(crd, snx, snf, a1pack, qpack, psh, pbh);
    redmix_kernel<<<256, 256, 0, stream>>>(psh, pbh, part, M1, M2, logits, cur, qpack,
                                           it == 0 ? 32 : 256, it == 4 ? 1 : 0);
  }
}